// Round 8
// baseline (393.618 us; speedup 1.0000x reference)
//
#include <hip/hip_runtime.h>
#include <hip/hip_bf16.h>

#define Bdim 64
#define Tdim 96
#define Pdim 256
#define Hdim 128
#define Gdim 512   // 4*H
#define Odim 24
#define BH   32    // batches per stream (two streams per block)

typedef _Float16 f16x8 __attribute__((ext_vector_type(8)));
typedef float    f32x16 __attribute__((ext_vector_type(16)));
typedef float    f32x2  __attribute__((ext_vector_type(2)));

union H8 { uint4 u4; unsigned short s[8]; _Float16 h[8]; f16x8 v; };
union HS { _Float16 h; unsigned short s; };

__device__ __forceinline__ float exp2_fast(float x) {
#if __has_builtin(__builtin_amdgcn_exp2f)
    return __builtin_amdgcn_exp2f(x);
#else
    return __expf(x * 0.6931471805599453f);
#endif
}

// One block per point p (grid=256, 1024 threads = 16 waves, 1 block/CU).
// Wave w owns r' rows [32w,32w+32); r' = 4*k+gate (i,f,g,o): regs 4q..4q+3 of a
// lane = 4 gates of one (b,k). B=64 in two 32-batch streams, half a step apart.
//
// R8 structural fix: per phase the issue order is
//   [8 ds_read_b128, no wait] -> [epilogue VALU of the OTHER stream (uses only
//   registers), h results kept in regs] -> sched_barrier(0) -> [waitcnt + 9
//   dependent MFMAs] -> [4 ds_write_b16 of h].
// Rationale (R5-R7 counters): VALU busy/step ~4500 cy (trans at 1/8 rate),
// LDS pipe ~3000, MFMA ~2500, yet wall ~8280 -> pipes were serializing because
// the old order (reads -> MFMA(waitcnt) -> epilogue) blocked the in-order wave
// at lgkmcnt before it could issue the independent epilogue. Issuing the
// epilogue before the MFMA waitcnt overlaps the VALU pipe with the LDS drain.
//
// h layout: row b = 256 B = 16 chunks of 16 B, chunk c at position c^(b&15)
// (XOR swizzle; read addr folds to base ^ (ks<<5), one v_xor per read).
// Math: log2e-prescaled weights (2log2e for g), gx fused as 9th MFMA K-step,
// scaled-domain cell state, paired-rcp epilogue (6 trans per (b,k)).
__global__ __launch_bounds__(1024, 4)
void lstm_fused(const float* __restrict__ x,
                const float* __restrict__ W_ih,
                const float* __restrict__ W_hh,
                const float* __restrict__ b_ih,
                const float* __restrict__ b_hh,
                const float* __restrict__ W_fc,
                const float* __restrict__ b_fc,
                float* __restrict__ out)
{
    __shared__ unsigned short hb0[2][BH * Hdim];  // stream0 h, double-buffered, swizzled
    __shared__ unsigned short hb1[2][BH * Hdim];  // stream1 h, double-buffered, swizzled

    const int p   = blockIdx.x;
    const int tid = threadIdx.x;
    const int w   = tid >> 6;    // wave 0..15
    const int l31 = tid & 31;
    const int hi  = (tid >> 5) & 1;

    const float L1 = 1.4426950408889634f;  // log2(e)
    const float L2 = 2.0f * L1;

    for (int i = tid; i < 2 * BH * Hdim; i += 1024) ((unsigned short*)hb0)[i] = 0;
    for (int i = tid; i < 2 * BH * Hdim; i += 1024) ((unsigned short*)hb1)[i] = 0;

    // ---- preload shared A fragments (time-invariant): W_hh rows + gx row ----
    f16x8 afr[9];
    {
        const int rp   = w * 32 + l31;                // r'
        const int orow = ((rp & 3) << 7) | (rp >> 2); // gate*128 + k
        const float sc = ((rp & 3) == 2) ? L2 : L1;   // g gate: 2*log2e
        const float* rowp = W_hh + (size_t)p * Gdim * Hdim + (size_t)orow * Hdim;
        #pragma unroll
        for (int ks = 0; ks < 8; ++ks) {
            int k0 = ks * 16 + hi * 8;
            float4 va = *(const float4*)(rowp + k0);
            float4 vb = *(const float4*)(rowp + k0 + 4);
            H8 u;
            u.h[0] = (_Float16)(sc * va.x); u.h[1] = (_Float16)(sc * va.y);
            u.h[2] = (_Float16)(sc * va.z); u.h[3] = (_Float16)(sc * va.w);
            u.h[4] = (_Float16)(sc * vb.x); u.h[5] = (_Float16)(sc * vb.y);
            u.h[6] = (_Float16)(sc * vb.z); u.h[7] = (_Float16)(sc * vb.w);
            afr[ks] = u.v;
        }
        H8 u9;
        #pragma unroll
        for (int j = 0; j < 8; ++j) u9.s[j] = 0;
        if (hi == 0) {
            u9.h[0] = (_Float16)(sc * W_ih[(size_t)p * Gdim + orow]);
            u9.h[1] = (_Float16)(sc * (b_ih[(size_t)p * Gdim + orow] +
                                       b_hh[(size_t)p * Gdim + orow]));
        }
        afr[8] = u9.v;
    }

    // read address base: addr(ks) = rbase ^ (ks<<5)   (c = 2ks+hi)
    const int rbase = (l31 << 8) | (((l31 & 15) << 4) ^ (hi << 4));
    // write base (elements): chunk w of row l31, slot 2q+hi
    const int wbase = (l31 << 7) + ((w ^ (l31 & 15)) << 3) + hi;

    // epilogue for q-pair (q=2j,2j+1): acc -> new c (scaled domain), returns h pair
    auto ep_pair = [&](const f32x16& a, int j, f32x2* cr) -> f32x2 {
        f32x2 yi = {a[8 * j + 0], a[8 * j + 4]};
        f32x2 yf = {a[8 * j + 1], a[8 * j + 5]};
        f32x2 yg = {a[8 * j + 2], a[8 * j + 6]};   // prescaled by 2*log2e
        f32x2 yo = {a[8 * j + 3], a[8 * j + 7]};
        f32x2 Ef = {exp2_fast(-yf.x), exp2_fast(-yf.y)};
        f32x2 Ei = {exp2_fast(-yi.x), exp2_fast(-yi.y)};
        f32x2 Eg = {exp2_fast(yg.x),  exp2_fast(yg.y)};
        f32x2 t1 = Ef + 1.0f;
        f32x2 t2 = Ei + 1.0f;
        f32x2 t3 = Eg + 1.0f;
        f32x2 t4 = Eg - 1.0f;
        f32x2 den = (t1 * t2) * t3;
        f32x2 num = (cr[j] * t2) * t3 + (L2 * t4) * t1;
        float D = den.x * den.y;
        float r = __builtin_amdgcn_rcpf(D);
        f32x2 inv = {r * den.y, r * den.x};
        f32x2 cn  = num * inv;
        cn.x = __builtin_amdgcn_fmed3f(cn.x, -30.0f, 30.0f);
        cn.y = __builtin_amdgcn_fmed3f(cn.y, -30.0f, 30.0f);
        cr[j] = cn;
        f32x2 Eo = {exp2_fast(-yo.x), exp2_fast(-yo.y)};
        f32x2 Ec = {exp2_fast(cn.x),  exp2_fast(cn.y)};
        f32x2 d2 = (Eo + 1.0f) * (Ec + 1.0f);
        float D2 = d2.x * d2.y;
        float r2 = __builtin_amdgcn_rcpf(D2);
        f32x2 j2 = {r2 * d2.y, r2 * d2.x};
        return (Ec - 1.0f) * j2;
    };

    // one phase: ds_reads(rb) -> epilogue(ar) -> MFMAs(acc) -> ds_writes(wb)
    auto phase = [&](const unsigned short* rb, unsigned short* wb,
                     f32x16& acc, const f32x16& ar, f32x2* cr, float xv,
                     bool doGemm, bool doEp) {
        H8 f0, f1, f2, f3, f4, f5, f6, f7;
        const char* hc = (const char*)rb;
        if (doGemm) {
            f0.u4 = *(const uint4*)(hc + (rbase ^ (0 << 5)));
            f1.u4 = *(const uint4*)(hc + (rbase ^ (1 << 5)));
            f2.u4 = *(const uint4*)(hc + (rbase ^ (2 << 5)));
            f3.u4 = *(const uint4*)(hc + (rbase ^ (3 << 5)));
            f4.u4 = *(const uint4*)(hc + (rbase ^ (4 << 5)));
            f5.u4 = *(const uint4*)(hc + (rbase ^ (5 << 5)));
            f6.u4 = *(const uint4*)(hc + (rbase ^ (6 << 5)));
            f7.u4 = *(const uint4*)(hc + (rbase ^ (7 << 5)));
        }
        f32x2 hv0, hv1;
        if (doEp) {
            hv0 = ep_pair(ar, 0, cr);
            hv1 = ep_pair(ar, 1, cr);
        }
        __builtin_amdgcn_sched_barrier(0);   // keep MFMA/waitcnt below the epilogue VALU
        if (doGemm) {
            f32x16 z;
            #pragma unroll
            for (int j = 0; j < 16; ++j) z[j] = 0.f;
            acc = __builtin_amdgcn_mfma_f32_32x32x16_f16(afr[0], f0.v, z, 0, 0, 0);
            acc = __builtin_amdgcn_mfma_f32_32x32x16_f16(afr[1], f1.v, acc, 0, 0, 0);
            acc = __builtin_amdgcn_mfma_f32_32x32x16_f16(afr[2], f2.v, acc, 0, 0, 0);
            acc = __builtin_amdgcn_mfma_f32_32x32x16_f16(afr[3], f3.v, acc, 0, 0, 0);
            acc = __builtin_amdgcn_mfma_f32_32x32x16_f16(afr[4], f4.v, acc, 0, 0, 0);
            acc = __builtin_amdgcn_mfma_f32_32x32x16_f16(afr[5], f5.v, acc, 0, 0, 0);
            acc = __builtin_amdgcn_mfma_f32_32x32x16_f16(afr[6], f6.v, acc, 0, 0, 0);
            acc = __builtin_amdgcn_mfma_f32_32x32x16_f16(afr[7], f7.v, acc, 0, 0, 0);
            H8 bg;
            #pragma unroll
            for (int j = 0; j < 8; ++j) bg.s[j] = 0;
            if (hi == 0) { bg.h[0] = (_Float16)xv; bg.h[1] = (_Float16)1.0f; }
            acc = __builtin_amdgcn_mfma_f32_32x32x16_f16(afr[8], bg.v, acc, 0, 0, 0);
        }
        if (doEp) {
            HS ha, hbv, hcv, hd;
            ha.h  = (_Float16)hv0.x;
            hbv.h = (_Float16)hv0.y;
            hcv.h = (_Float16)hv1.x;
            hd.h  = (_Float16)hv1.y;
            wb[wbase + 0] = ha.s;    // q=0
            wb[wbase + 2] = hbv.s;   // q=1
            wb[wbase + 4] = hcv.s;   // q=2
            wb[wbase + 6] = hd.s;    // q=3
        }
    };

    f32x2 cre0[2] = {f32x2{0.f, 0.f}, f32x2{0.f, 0.f}};
    f32x2 cre1[2] = {f32x2{0.f, 0.f}, f32x2{0.f, 0.f}};
    f32x16 acc0, acc1;
    #pragma unroll
    for (int j = 0; j < 16; ++j) { acc0[j] = 0.f; acc1[j] = 0.f; }

    const float* xp0 = x + (size_t)((0 * BH + l31) * Tdim) * Pdim + p;
    const float* xp1 = x + (size_t)((1 * BH + l31) * Tdim) * Pdim + p;
    float xv1 = xp1[0];

    __syncthreads();

    // prologue: gemm_s0(0) only (reads zeros)
    {
        float xv0 = xp0[0];
        phase(hb0[0], hb1[0], acc0, acc1, cre1, xv0, true, false);
    }
    __syncthreads();

    for (int t = 0; t < Tdim; ++t) {
        const int P  = t & 1;
        const int tn = (t + 1 < Tdim) ? (t + 1) : t;
        float xn0 = xp0[(size_t)tn * Pdim];   // for gemm_s0(t+1)

        // phase B(t): gemm_s1(t) reads hb1[P]  ||  ep_s0(t) writes hb0[P^1]
        phase(hb1[P], hb0[P ^ 1], acc1, acc0, cre0, xv1, true, true);
        __syncthreads();

        float xn1 = xp1[(size_t)tn * Pdim];   // for gemm_s1(t+1)
        if (t + 1 < Tdim) {
            // phase A(t+1): gemm_s0(t+1) reads hb0[P^1] || ep_s1(t) writes hb1[P^1]
            phase(hb0[P ^ 1], hb1[P ^ 1], acc0, acc1, cre1, xn0, true, true);
        } else {
            // final: ep_s1(95) only -> hb1[0]
            phase(hb0[P ^ 1], hb1[P ^ 1], acc0, acc1, cre1, 0.f, false, true);
        }
        __syncthreads();
        xv1 = xn1;
    }
    // final h: stream0 in hb0[0], stream1 in hb1[0] (swizzled layout)

    // ---- FC: out[b][o][p] = sum_k W_fc[p][o][k]*h[b][k] + b_fc[p][o] ----
    const float* wfc = W_fc + (size_t)p * Odim * Hdim;
    const float* bfc = b_fc + (size_t)p * Odim;
    for (int i = tid; i < Bdim * Odim; i += 1024) {
        int o = i % Odim;
        int b = i / Odim;            // global batch 0..63
        int bl = (b < BH) ? b : (b - BH);
        const unsigned short* hr = (b < BH) ? (hb0[0] + (bl << 7))
                                            : (hb1[0] + (bl << 7));
        float s = bfc[o];
        const float* wr = wfc + o * Hdim;
        #pragma unroll 8
        for (int k2 = 0; k2 < Hdim; ++k2) {
            int idx = (((k2 >> 3) ^ (bl & 15)) << 3) + (k2 & 7);   // unswizzle
            HS s2; s2.s = hr[idx];
            s = __builtin_fmaf(wr[k2], (float)s2.h, s);
        }
        out[(size_t)b * Odim * Pdim + (size_t)o * Pdim + p] = s;
    }
}

extern "C" void kernel_launch(void* const* d_in, const int* in_sizes, int n_in,
                              void* d_out, int out_size, void* d_ws, size_t ws_size,
                              hipStream_t stream) {
    const float* x    = (const float*)d_in[0];
    const float* W_ih = (const float*)d_in[1];
    const float* W_hh = (const float*)d_in[2];
    const float* b_ih = (const float*)d_in[3];
    const float* b_hh = (const float*)d_in[4];
    const float* W_fc = (const float*)d_in[5];
    const float* b_fc = (const float*)d_in[6];
    float* out = (float*)d_out;

    lstm_fused<<<dim3(Pdim), dim3(1024), 0, stream>>>(x, W_ih, W_hh, b_ih, b_hh, W_fc, b_fc, out);
}